// Round 1
// baseline (800.508 us; speedup 1.0000x reference)
//
#include <hip/hip_runtime.h>
#include <hip/hip_bf16.h>
#include <math.h>

// ---------- problem constants ----------
#define H 1024
#define F 4096
#define E 8
#define NTOK 4096          // B*S = 2*2048
#define CAP 4096           // token-list capacity per expert (hard upper bound)
#define MCAP 2048          // max rows per expert covered by GEMM grid (counts ~1024)
#define NPAIR 8192         // total token-expert pairs = NTOK * K

typedef unsigned short u16;
typedef __bf16 bf16x8 __attribute__((ext_vector_type(8)));
typedef float f32x4 __attribute__((ext_vector_type(4)));
typedef u16 u16x8 __attribute__((ext_vector_type(8)));

__device__ inline u16 f2bf(float f) {   // RNE f32 -> bf16
    union { float f; unsigned u; } v; v.f = f;
    unsigned r = v.u + 0x7fffu + ((v.u >> 16) & 1u);
    return (u16)(r >> 16);
}

// ---------- x fp32 -> bf16 ----------
__global__ void cvt_x(const float* __restrict__ x, u16* __restrict__ xb, int n4) {
    int j = blockIdx.x * blockDim.x + threadIdx.x;
    if (j >= n4) return;
    float4 v = ((const float4*)x)[j];
    u16x8 dummy; (void)dummy;
    u16* o = xb + (size_t)j * 4;
    o[0] = f2bf(v.x); o[1] = f2bf(v.y); o[2] = f2bf(v.z); o[3] = f2bf(v.w);
}

// ---------- per-expert transpose + convert: in [R][C] f32 -> out [C][R] bf16 ----------
__global__ void transpose_cvt(const float* __restrict__ in, u16* __restrict__ out,
                              int R, int C) {
    const float* ip = in + (size_t)blockIdx.z * R * C;
    u16* op = out + (size_t)blockIdx.z * R * C;
    __shared__ float tile[32][33];
    int c0 = blockIdx.x * 32, r0 = blockIdx.y * 32;
    int tx = threadIdx.x, ty = threadIdx.y;    // 32 x 8
    for (int j = ty; j < 32; j += 8)
        tile[j][tx] = ip[(size_t)(r0 + j) * C + c0 + tx];
    __syncthreads();
    for (int j = ty; j < 32; j += 8)
        op[(size_t)(c0 + j) * R + r0 + tx] = f2bf(tile[tx][j]);
}

// ---------- router: fp32 scores, softmax top-2, bucket by expert ----------
__global__ void router_kernel(const float* __restrict__ x, const float* __restrict__ rw,
                              const float* __restrict__ rb, int* __restrict__ counts,
                              int* __restrict__ tok_e, float* __restrict__ wgt_e) {
    int tok = blockIdx.x;
    int lane = threadIdx.x;       // 64 lanes, one wave per token
    float s[E] = {0.f,0.f,0.f,0.f,0.f,0.f,0.f,0.f};
    for (int r = 0; r < 4; ++r) {
        int h = r * 256 + lane * 4;
        float4 xv = *(const float4*)&x[(size_t)tok * H + h];
        const float* xf = (const float*)&xv;
        #pragma unroll
        for (int u = 0; u < 4; ++u) {
            float xs = xf[u];
            const float4* row = (const float4*)&rw[(size_t)(h + u) * E];
            float4 a = row[0], b = row[1];
            s[0] += xs * a.x; s[1] += xs * a.y; s[2] += xs * a.z; s[3] += xs * a.w;
            s[4] += xs * b.x; s[5] += xs * b.y; s[6] += xs * b.z; s[7] += xs * b.w;
        }
    }
    #pragma unroll
    for (int off = 32; off > 0; off >>= 1)
        #pragma unroll
        for (int e2 = 0; e2 < E; ++e2) s[e2] += __shfl_down(s[e2], off);
    if (lane == 0) {
        #pragma unroll
        for (int e2 = 0; e2 < E; ++e2) s[e2] += rb[e2];
        // top-2 with lowest-index tie-break (matches jax.lax.top_k)
        int i0 = 0;
        #pragma unroll
        for (int e2 = 1; e2 < E; ++e2) if (s[e2] > s[i0]) i0 = e2;
        int i1 = (i0 == 0) ? 1 : 0;
        #pragma unroll
        for (int e2 = 0; e2 < E; ++e2) if (e2 != i0 && s[e2] > s[i1]) i1 = e2;
        // normalized top-2 softmax weights: p0 = exp(s0)/(exp(s0)+exp(s1))
        float p0 = 1.0f / (1.0f + expf(s[i1] - s[i0]));
        float p1 = 1.0f - p0;
        int pos0 = atomicAdd(&counts[i0], 1);
        tok_e[i0 * CAP + pos0] = tok; wgt_e[i0 * CAP + pos0] = p0;
        int pos1 = atomicAdd(&counts[i1], 1);
        tok_e[i1 * CAP + pos1] = tok; wgt_e[i1 * CAP + pos1] = p1;
    }
}

// ---------- tiny exclusive scan over E counters ----------
__global__ void scan_kernel(const int* __restrict__ counts, int* __restrict__ offsets) {
    if (threadIdx.x == 0 && blockIdx.x == 0) {
        int acc = 0;
        for (int e2 = 0; e2 < E; ++e2) { offsets[e2] = acc; acc += counts[e2]; }
    }
}

// ---------- GEMM tile config ----------
#define BM 128
#define BN 128
#define BK 32
#define LDP 40   // padded LDS pitch (u16): +8 -> 2-way bank aliasing only (free)

// GEMM1: hrow = gelu( Xg[e] @ w1[e] + b1[e] ), A gathered from xb by token list.
__global__ void gemm1_kernel(const u16* __restrict__ xb, const u16* __restrict__ w1t,
                             const float* __restrict__ b1,
                             const int* __restrict__ counts, const int* __restrict__ offsets,
                             const int* __restrict__ tok_e, u16* __restrict__ hbuf) {
    int e = blockIdx.z;
    int rows = counts[e];
    int m0 = blockIdx.y * BM;
    if (m0 >= rows) return;
    int n0 = blockIdx.x * BN;
    int off = offsets[e];
    const u16* wB = w1t + (size_t)e * F * H;   // [F][H] row-major = B^T

    __shared__ u16 As[BM][LDP];
    __shared__ u16 Bs[BN][LDP];

    int tid = threadIdx.x;
    int lane = tid & 63;
    int w = tid >> 6;
    int wr = w >> 1, wc = w & 1;

    int ar0 = tid >> 2, ac0 = tid & 3;    // staged chunk 0: row ar0, 16B chunk ac0
    int ar1 = ar0 + 64;                    // staged chunk 1
    int ia0 = m0 + ar0; if (ia0 > rows - 1) ia0 = rows - 1;
    int ia1 = m0 + ar1; if (ia1 > rows - 1) ia1 = rows - 1;
    int t0 = tok_e[e * CAP + ia0];
    int t1 = tok_e[e * CAP + ia1];
    const u16* aR0 = xb + (size_t)t0 * H + ac0 * 8;
    const u16* aR1 = xb + (size_t)t1 * H + ac0 * 8;
    const u16* bR0 = wB + (size_t)(n0 + ar0) * H + ac0 * 8;
    const u16* bR1 = wB + (size_t)(n0 + ar1) * H + ac0 * 8;

    f32x4 acc[4][4] = {};

    for (int k0 = 0; k0 < H; k0 += BK) {
        u16x8 av0 = *(const u16x8*)(aR0 + k0);
        u16x8 av1 = *(const u16x8*)(aR1 + k0);
        u16x8 bv0 = *(const u16x8*)(bR0 + k0);
        u16x8 bv1 = *(const u16x8*)(bR1 + k0);
        __syncthreads();
        *(u16x8*)&As[ar0][ac0 * 8] = av0;
        *(u16x8*)&As[ar1][ac0 * 8] = av1;
        *(u16x8*)&Bs[ar0][ac0 * 8] = bv0;
        *(u16x8*)&Bs[ar1][ac0 * 8] = bv1;
        __syncthreads();
        bf16x8 af[4], bfr[4];
        int fr = lane & 15, fk = (lane >> 4) * 8;
        #pragma unroll
        for (int m = 0; m < 4; ++m) af[m] = *(bf16x8*)&As[wr * 64 + m * 16 + fr][fk];
        #pragma unroll
        for (int n = 0; n < 4; ++n) bfr[n] = *(bf16x8*)&Bs[wc * 64 + n * 16 + fr][fk];
        #pragma unroll
        for (int m = 0; m < 4; ++m)
            #pragma unroll
            for (int n = 0; n < 4; ++n)
                acc[m][n] = __builtin_amdgcn_mfma_f32_16x16x32_bf16(af[m], bfr[n], acc[m][n], 0, 0, 0);
    }

    const float* b1e = b1 + (size_t)e * F;
    int cr = (lane >> 4) * 4;
    int cc = lane & 15;
    #pragma unroll
    for (int m = 0; m < 4; ++m) {
        int gr = m0 + wr * 64 + m * 16 + cr;
        #pragma unroll
        for (int n = 0; n < 4; ++n) {
            int gc = n0 + wc * 64 + n * 16 + cc;
            float bias = b1e[gc];
            #pragma unroll
            for (int j = 0; j < 4; ++j) {
                int r = gr + j;
                if (r < rows) {
                    float v = acc[m][n][j] + bias;
                    float g = 0.5f * v * (1.0f + erff(v * 0.70710678118654752f));
                    hbuf[(size_t)(off + r) * F + gc] = f2bf(g);
                }
            }
        }
    }
}

// GEMM2: out[tok] += wgt * ( Hrows @ w2[e] + b2[e] )
__global__ void gemm2_kernel(const u16* __restrict__ hbuf, const u16* __restrict__ w2t,
                             const float* __restrict__ b2,
                             const int* __restrict__ counts, const int* __restrict__ offsets,
                             const int* __restrict__ tok_e, const float* __restrict__ wgt_e,
                             float* __restrict__ out) {
    int e = blockIdx.z;
    int rows = counts[e];
    int m0 = blockIdx.y * BM;
    if (m0 >= rows) return;
    int n0 = blockIdx.x * BN;
    int off = offsets[e];
    const u16* wB = w2t + (size_t)e * H * F;   // [H][F] row-major = B^T

    __shared__ u16 As[BM][LDP];
    __shared__ u16 Bs[BN][LDP];

    int tid = threadIdx.x;
    int lane = tid & 63;
    int w = tid >> 6;
    int wr = w >> 1, wc = w & 1;

    int ar0 = tid >> 2, ac0 = tid & 3;
    int ar1 = ar0 + 64;
    int ia0 = m0 + ar0; if (ia0 > rows - 1) ia0 = rows - 1;
    int ia1 = m0 + ar1; if (ia1 > rows - 1) ia1 = rows - 1;
    const u16* aR0 = hbuf + (size_t)(off + ia0) * F + ac0 * 8;
    const u16* aR1 = hbuf + (size_t)(off + ia1) * F + ac0 * 8;
    const u16* bR0 = wB + (size_t)(n0 + ar0) * F + ac0 * 8;
    const u16* bR1 = wB + (size_t)(n0 + ar1) * F + ac0 * 8;

    f32x4 acc[4][4] = {};

    for (int k0 = 0; k0 < F; k0 += BK) {
        u16x8 av0 = *(const u16x8*)(aR0 + k0);
        u16x8 av1 = *(const u16x8*)(aR1 + k0);
        u16x8 bv0 = *(const u16x8*)(bR0 + k0);
        u16x8 bv1 = *(const u16x8*)(bR1 + k0);
        __syncthreads();
        *(u16x8*)&As[ar0][ac0 * 8] = av0;
        *(u16x8*)&As[ar1][ac0 * 8] = av1;
        *(u16x8*)&Bs[ar0][ac0 * 8] = bv0;
        *(u16x8*)&Bs[ar1][ac0 * 8] = bv1;
        __syncthreads();
        bf16x8 af[4], bfr[4];
        int fr = lane & 15, fk = (lane >> 4) * 8;
        #pragma unroll
        for (int m = 0; m < 4; ++m) af[m] = *(bf16x8*)&As[wr * 64 + m * 16 + fr][fk];
        #pragma unroll
        for (int n = 0; n < 4; ++n) bfr[n] = *(bf16x8*)&Bs[wc * 64 + n * 16 + fr][fk];
        #pragma unroll
        for (int m = 0; m < 4; ++m)
            #pragma unroll
            for (int n = 0; n < 4; ++n)
                acc[m][n] = __builtin_amdgcn_mfma_f32_16x16x32_bf16(af[m], bfr[n], acc[m][n], 0, 0, 0);
    }

    const float* b2e = b2 + (size_t)e * H;
    int cr = (lane >> 4) * 4;
    int cc = lane & 15;
    #pragma unroll
    for (int m = 0; m < 4; ++m) {
        int gr = m0 + wr * 64 + m * 16 + cr;
        #pragma unroll
        for (int j = 0; j < 4; ++j) {
            int r = gr + j;
            if (r < rows) {
                int tok = tok_e[e * CAP + r];
                float wgt = wgt_e[e * CAP + r];
                #pragma unroll
                for (int n = 0; n < 4; ++n) {
                    int gc = n0 + wc * 64 + n * 16 + cc;
                    float v = (acc[m][n][j] + b2e[gc]) * wgt;
                    atomicAdd(&out[(size_t)tok * H + gc], v);
                }
            }
        }
    }
}

// ---------- launch ----------
extern "C" void kernel_launch(void* const* d_in, const int* in_sizes, int n_in,
                              void* d_out, int out_size, void* d_ws, size_t ws_size,
                              hipStream_t stream) {
    const float* x  = (const float*)d_in[0];
    const float* rw = (const float*)d_in[1];
    const float* rb = (const float*)d_in[2];
    const float* w1 = (const float*)d_in[3];
    const float* b1 = (const float*)d_in[4];
    const float* w2 = (const float*)d_in[5];
    const float* b2 = (const float*)d_in[6];
    float* out = (float*)d_out;

    char* ws = (char*)d_ws;
    size_t o = 0;
    u16* xb   = (u16*)(ws + o); o += (size_t)NTOK * H * 2;      // 8 MB
    u16* w1t  = (u16*)(ws + o); o += (size_t)E * F * H * 2;     // 64 MB  [E][F][H]
    u16* w2t  = (u16*)(ws + o); o += (size_t)E * H * F * 2;     // 64 MB  [E][H][F]
    u16* hbuf = (u16*)(ws + o); o += (size_t)NPAIR * F * 2;     // 64 MB  [8192][F]
    int*   tok_e = (int*)(ws + o);   o += (size_t)E * CAP * 4;  // 128 KB
    float* wgt_e = (float*)(ws + o); o += (size_t)E * CAP * 4;  // 128 KB
    int*   counts  = (int*)(ws + o); o += E * 4;
    int*   offsets = (int*)(ws + o); o += E * 4;

    hipMemsetAsync(counts, 0, 2 * E * sizeof(int), stream);
    hipMemsetAsync(out, 0, (size_t)out_size * sizeof(float), stream);

    cvt_x<<<(NTOK * H / 4 + 255) / 256, 256, 0, stream>>>(x, xb, NTOK * H / 4);
    transpose_cvt<<<dim3(F / 32, H / 32, E), dim3(32, 8), 0, stream>>>(w1, w1t, H, F);
    transpose_cvt<<<dim3(H / 32, F / 32, E), dim3(32, 8), 0, stream>>>(w2, w2t, F, H);
    router_kernel<<<NTOK, 64, 0, stream>>>(x, rw, rb, counts, tok_e, wgt_e);
    scan_kernel<<<1, 64, 0, stream>>>(counts, offsets);
    gemm1_kernel<<<dim3(F / BN, MCAP / BM, E), 256, 0, stream>>>(xb, w1t, b1, counts, offsets, tok_e, hbuf);
    gemm2_kernel<<<dim3(H / BN, MCAP / BM, E), 256, 0, stream>>>(hbuf, w2t, b2, counts, offsets, tok_e, wgt_e, out);
}

// Round 2
// 776.154 us; speedup vs baseline: 1.0314x; 1.0314x over previous
//
#include <hip/hip_runtime.h>
#include <hip/hip_bf16.h>
#include <math.h>

// ---------- problem constants ----------
#define H 1024
#define F 4096
#define E 8
#define NTOK 4096          // B*S
#define CAP 4096           // token-list capacity per expert
#define NPAIR 8192         // NTOK * K

typedef unsigned short u16;
typedef __bf16 bf16x8 __attribute__((ext_vector_type(8)));
typedef float f32x4 __attribute__((ext_vector_type(4)));
typedef u16 u16x8 __attribute__((ext_vector_type(8)));
typedef u16 u16x4 __attribute__((ext_vector_type(4)));

__device__ inline u16 f2bf(float f) {   // RNE f32 -> bf16
    union { float f; unsigned u; } v; v.f = f;
    unsigned r = v.u + 0x7fffu + ((v.u >> 16) & 1u);
    return (u16)(r >> 16);
}

// async global->LDS, 16B per lane; LDS dest is wave-uniform base + lane*16
__device__ inline void gload_lds16(const void* g, void* l) {
    __builtin_amdgcn_global_load_lds(
        (const __attribute__((address_space(1))) unsigned*)g,
        (__attribute__((address_space(3))) unsigned*)l, 16, 0, 0);
}

// ---------- x fp32 -> bf16 (vectorized: 8 elems/thread, 16B store) ----------
__global__ void cvt_x(const float* __restrict__ x, u16* __restrict__ xb, int n8) {
    int j = blockIdx.x * blockDim.x + threadIdx.x;
    if (j >= n8) return;
    const float4* p = (const float4*)(x + (size_t)j * 8);
    float4 a = p[0], b = p[1];
    u16x8 o;
    o[0] = f2bf(a.x); o[1] = f2bf(a.y); o[2] = f2bf(a.z); o[3] = f2bf(a.w);
    o[4] = f2bf(b.x); o[5] = f2bf(b.y); o[6] = f2bf(b.z); o[7] = f2bf(b.w);
    *(u16x8*)(xb + (size_t)j * 8) = o;
}

// ---------- per-expert transpose+convert: in [R][C] f32 -> out [C][R] bf16 ----------
// 64x64 tile, float4 loads, u16x8 (16B) stores.
__global__ void transpose_cvt(const float* __restrict__ in, u16* __restrict__ out,
                              int R, int C) {
    const float* ip = in + (size_t)blockIdx.z * R * C;
    u16* op = out + (size_t)blockIdx.z * R * C;
    __shared__ float tile[64][65];
    int r0 = blockIdx.y * 64, c0 = blockIdx.x * 64;
    int tid = threadIdx.x;                 // 256 threads
    int rr = tid >> 4;                     // 0..15
    int cc4 = (tid & 15) * 4;              // 0..60
    #pragma unroll
    for (int it = 0; it < 4; ++it) {
        int r = rr + it * 16;
        float4 v = *(const float4*)&ip[(size_t)(r0 + r) * C + c0 + cc4];
        tile[r][cc4 + 0] = v.x; tile[r][cc4 + 1] = v.y;
        tile[r][cc4 + 2] = v.z; tile[r][cc4 + 3] = v.w;
    }
    __syncthreads();
    int co = tid >> 3;                     // 0..31
    int ro8 = (tid & 7) * 8;               // 0..56
    #pragma unroll
    for (int it = 0; it < 2; ++it) {
        int c = co + it * 32;
        u16x8 o;
        #pragma unroll
        for (int u = 0; u < 8; ++u) o[u] = f2bf(tile[ro8 + u][c]);
        *(u16x8*)&op[(size_t)(c0 + c) * R + r0 + ro8] = o;
    }
}

// ---------- router: fp32 scores, softmax top-2, bucket by expert ----------
__global__ void router_kernel(const float* __restrict__ x, const float* __restrict__ rw,
                              const float* __restrict__ rb, int* __restrict__ counts,
                              int* __restrict__ tok_e, float* __restrict__ wgt_e) {
    int tok = blockIdx.x;
    int lane = threadIdx.x;       // one wave per token
    float s[E] = {0.f,0.f,0.f,0.f,0.f,0.f,0.f,0.f};
    for (int r = 0; r < 4; ++r) {
        int h = r * 256 + lane * 4;
        float4 xv = *(const float4*)&x[(size_t)tok * H + h];
        const float* xf = (const float*)&xv;
        #pragma unroll
        for (int u = 0; u < 4; ++u) {
            float xs = xf[u];
            const float4* row = (const float4*)&rw[(size_t)(h + u) * E];
            float4 a = row[0], b = row[1];
            s[0] += xs * a.x; s[1] += xs * a.y; s[2] += xs * a.z; s[3] += xs * a.w;
            s[4] += xs * b.x; s[5] += xs * b.y; s[6] += xs * b.z; s[7] += xs * b.w;
        }
    }
    #pragma unroll
    for (int off = 32; off > 0; off >>= 1)
        #pragma unroll
        for (int e2 = 0; e2 < E; ++e2) s[e2] += __shfl_down(s[e2], off);
    if (lane == 0) {
        #pragma unroll
        for (int e2 = 0; e2 < E; ++e2) s[e2] += rb[e2];
        int i0 = 0;
        #pragma unroll
        for (int e2 = 1; e2 < E; ++e2) if (s[e2] > s[i0]) i0 = e2;
        int i1 = (i0 == 0) ? 1 : 0;
        #pragma unroll
        for (int e2 = 0; e2 < E; ++e2) if (e2 != i0 && s[e2] > s[i1]) i1 = e2;
        float p0 = 1.0f / (1.0f + expf(s[i1] - s[i0]));
        float p1 = 1.0f - p0;
        int pos0 = atomicAdd(&counts[i0], 1);
        tok_e[i0 * CAP + pos0] = tok; wgt_e[i0 * CAP + pos0] = p0;
        int pos1 = atomicAdd(&counts[i1], 1);
        tok_e[i1 * CAP + pos1] = tok; wgt_e[i1 * CAP + pos1] = p1;
    }
}

__global__ void scan_kernel(const int* __restrict__ counts, int* __restrict__ offsets) {
    if (threadIdx.x == 0 && blockIdx.x == 0) {
        int acc = 0;
        for (int e2 = 0; e2 < E; ++e2) { offsets[e2] = acc; acc += counts[e2]; }
    }
}

// ---------- GEMM tile config (m97 structure) ----------
#define BM 128
#define BN 128
#define BK 32

// GEMM1: h = gelu( Xg[e] @ w1[e] + b1[e] );  A gathered via token list.
// MFMA operands swapped (C^T layout): lane owns 4 consecutive F-columns.
__global__ void gemm1_kernel(const u16* __restrict__ xb, const u16* __restrict__ w1t,
                             const float* __restrict__ b1,
                             const int* __restrict__ counts, const int* __restrict__ offsets,
                             const int* __restrict__ tok_e, u16* __restrict__ hbuf) {
    int e = blockIdx.z;
    int rows = counts[e];
    int m0 = blockIdx.y * BM;
    if (m0 >= rows) return;
    int n0 = blockIdx.x * BN;
    int off = offsets[e];
    const u16* wB = w1t + (size_t)e * F * H;   // [F][H] = B^T rows

    __shared__ u16 As[BM * BK];   // linear, 8KB (global_load_lds dest)
    __shared__ u16 Bs[BN * BK];

    int tid = threadIdx.x, lane = tid & 63, w = tid >> 6;
    int wr = w >> 1, wc = w & 1;

    // staging geometry: wave w covers 1KB chunks idx = 2w, 2w+1 (16 rows each)
    int i0 = w * 2, i1 = w * 2 + 1;
    int rA0 = i0 * 16 + (lane >> 2), rA1 = i1 * 16 + (lane >> 2);
    int cB = (lane & 3) * 8;
    int ia0 = m0 + rA0; if (ia0 >= rows) ia0 = rows - 1;
    int ia1 = m0 + rA1; if (ia1 >= rows) ia1 = rows - 1;
    const u16* aS0 = xb + (size_t)tok_e[e * CAP + ia0] * H + cB;
    const u16* aS1 = xb + (size_t)tok_e[e * CAP + ia1] * H + cB;
    const u16* bS0 = wB + (size_t)(n0 + rA0) * H + cB;
    const u16* bS1 = wB + (size_t)(n0 + rA1) * H + cB;
    u16* lA0 = As + i0 * 512;  u16* lA1 = As + i1 * 512;
    u16* lB0 = Bs + i0 * 512;  u16* lB1 = Bs + i1 * 512;

    int fr = lane & 15, fk = (lane >> 4) * 8;
    const u16* pa = As + (wr * 64 + fr) * BK + fk;
    const u16* pb = Bs + (wc * 64 + fr) * BK + fk;

    f32x4 acc[4][4] = {};

    for (int k0 = 0; k0 < H; k0 += BK) {
        __syncthreads();
        gload_lds16(aS0 + k0, lA0);
        gload_lds16(aS1 + k0, lA1);
        gload_lds16(bS0 + k0, lB0);
        gload_lds16(bS1 + k0, lB1);
        __syncthreads();
        bf16x8 af[4], bfr[4];
        #pragma unroll
        for (int m = 0; m < 4; ++m) af[m] = *(const bf16x8*)(pa + m * 16 * BK);
        #pragma unroll
        for (int n = 0; n < 4; ++n) bfr[n] = *(const bf16x8*)(pb + n * 16 * BK);
        #pragma unroll
        for (int m = 0; m < 4; ++m)
            #pragma unroll
            for (int n = 0; n < 4; ++n)   // swapped: D[f][tok]
                acc[m][n] = __builtin_amdgcn_mfma_f32_16x16x32_bf16(bfr[n], af[m], acc[m][n], 0, 0, 0);
    }

    // epilogue: lane owns token (lane&15), 4 consecutive f per (n): u16x4 stores
    const float* b1e = b1 + (size_t)e * F;
    int c4 = (lane >> 4) * 4;
    #pragma unroll
    for (int m = 0; m < 4; ++m) {
        int r = m0 + wr * 64 + m * 16 + fr;
        if (r < rows) {
            u16* hrow = hbuf + (size_t)(off + r) * F;
            #pragma unroll
            for (int n = 0; n < 4; ++n) {
                int gc = n0 + wc * 64 + n * 16 + c4;
                float4 bv = *(const float4*)&b1e[gc];
                const float* bvf = (const float*)&bv;
                u16x4 ov;
                #pragma unroll
                for (int j = 0; j < 4; ++j) {
                    float v = acc[m][n][j] + bvf[j];
                    float g = 0.5f * v * (1.0f + erff(v * 0.70710678118654752f));
                    ov[j] = f2bf(g);
                }
                *(u16x4*)&hrow[gc] = ov;
            }
        }
    }
}

// GEMM2: out[tok] += wgt * ( Hg @ w2[e] + b2[e] )
__global__ void gemm2_kernel(const u16* __restrict__ hbuf, const u16* __restrict__ w2t,
                             const float* __restrict__ b2,
                             const int* __restrict__ counts, const int* __restrict__ offsets,
                             const int* __restrict__ tok_e, const float* __restrict__ wgt_e,
                             float* __restrict__ out) {
    int e = blockIdx.z;
    int rows = counts[e];
    int m0 = blockIdx.y * BM;
    if (m0 >= rows) return;
    int n0 = blockIdx.x * BN;
    int off = offsets[e];
    const u16* wB = w2t + (size_t)e * H * F;   // [H][F] = B^T rows

    __shared__ u16 As[BM * BK];
    __shared__ u16 Bs[BN * BK];

    int tid = threadIdx.x, lane = tid & 63, w = tid >> 6;
    int wr = w >> 1, wc = w & 1;

    int i0 = w * 2, i1 = w * 2 + 1;
    int rA0 = i0 * 16 + (lane >> 2), rA1 = i1 * 16 + (lane >> 2);
    int cB = (lane & 3) * 8;
    int ia0 = m0 + rA0; if (ia0 >= rows) ia0 = rows - 1;
    int ia1 = m0 + rA1; if (ia1 >= rows) ia1 = rows - 1;
    const u16* aS0 = hbuf + (size_t)(off + ia0) * F + cB;
    const u16* aS1 = hbuf + (size_t)(off + ia1) * F + cB;
    const u16* bS0 = wB + (size_t)(n0 + rA0) * F + cB;
    const u16* bS1 = wB + (size_t)(n0 + rA1) * F + cB;
    u16* lA0 = As + i0 * 512;  u16* lA1 = As + i1 * 512;
    u16* lB0 = Bs + i0 * 512;  u16* lB1 = Bs + i1 * 512;

    int fr = lane & 15, fk = (lane >> 4) * 8;
    const u16* pa = As + (wr * 64 + fr) * BK + fk;
    const u16* pb = Bs + (wc * 64 + fr) * BK + fk;

    f32x4 acc[4][4] = {};

    for (int k0 = 0; k0 < F; k0 += BK) {
        __syncthreads();
        gload_lds16(aS0 + k0, lA0);
        gload_lds16(aS1 + k0, lA1);
        gload_lds16(bS0 + k0, lB0);
        gload_lds16(bS1 + k0, lB1);
        __syncthreads();
        bf16x8 af[4], bfr[4];
        #pragma unroll
        for (int m = 0; m < 4; ++m) af[m] = *(const bf16x8*)(pa + m * 16 * BK);
        #pragma unroll
        for (int n = 0; n < 4; ++n) bfr[n] = *(const bf16x8*)(pb + n * 16 * BK);
        #pragma unroll
        for (int m = 0; m < 4; ++m)
            #pragma unroll
            for (int n = 0; n < 4; ++n)
                acc[m][n] = __builtin_amdgcn_mfma_f32_16x16x32_bf16(bfr[n], af[m], acc[m][n], 0, 0, 0);
    }

    const float* b2e = b2 + (size_t)e * H;
    int c4 = (lane >> 4) * 4;
    #pragma unroll
    for (int m = 0; m < 4; ++m) {
        int r = m0 + wr * 64 + m * 16 + fr;
        if (r < rows) {
            int tok = tok_e[e * CAP + r];
            float wgt = wgt_e[e * CAP + r];
            float* orow = out + (size_t)tok * H;
            #pragma unroll
            for (int n = 0; n < 4; ++n) {
                int gc = n0 + wc * 64 + n * 16 + c4;
                float4 bv = *(const float4*)&b2e[gc];
                const float* bvf = (const float*)&bv;
                #pragma unroll
                for (int j = 0; j < 4; ++j)
                    atomicAdd(&orow[gc + j], (acc[m][n][j] + bvf[j]) * wgt);
            }
        }
    }
}

// ---------- launch ----------
extern "C" void kernel_launch(void* const* d_in, const int* in_sizes, int n_in,
                              void* d_out, int out_size, void* d_ws, size_t ws_size,
                              hipStream_t stream) {
    const float* x  = (const float*)d_in[0];
    const float* rw = (const float*)d_in[1];
    const float* rb = (const float*)d_in[2];
    const float* w1 = (const float*)d_in[3];
    const float* b1 = (const float*)d_in[4];
    const float* w2 = (const float*)d_in[5];
    const float* b2 = (const float*)d_in[6];
    float* out = (float*)d_out;

    char* ws = (char*)d_ws;
    size_t o = 0;
    u16* xb   = (u16*)(ws + o); o += (size_t)NTOK * H * 2;
    u16* w1t  = (u16*)(ws + o); o += (size_t)E * F * H * 2;     // [E][F][H]
    u16* w2t  = (u16*)(ws + o); o += (size_t)E * H * F * 2;     // [E][H][F]
    u16* hbuf = (u16*)(ws + o); o += (size_t)NPAIR * F * 2;
    int*   tok_e = (int*)(ws + o);   o += (size_t)E * CAP * 4;
    float* wgt_e = (float*)(ws + o); o += (size_t)E * CAP * 4;
    int*   counts  = (int*)(ws + o); o += E * 4;
    int*   offsets = (int*)(ws + o); o += E * 4;

    hipMemsetAsync(counts, 0, 2 * E * sizeof(int), stream);
    hipMemsetAsync(out, 0, (size_t)out_size * sizeof(float), stream);

    cvt_x<<<(NTOK * H / 8 + 255) / 256, 256, 0, stream>>>(x, xb, NTOK * H / 8);
    transpose_cvt<<<dim3(F / 64, H / 64, E), 256, 0, stream>>>(w1, w1t, H, F);
    transpose_cvt<<<dim3(H / 64, F / 64, E), 256, 0, stream>>>(w2, w2t, F, H);
    router_kernel<<<NTOK, 64, 0, stream>>>(x, rw, rb, counts, tok_e, wgt_e);
    scan_kernel<<<1, 64, 0, stream>>>(counts, offsets);
    gemm1_kernel<<<dim3(F / BN, CAP / BM, E), 256, 0, stream>>>(xb, w1t, b1, counts, offsets, tok_e, hbuf);
    gemm2_kernel<<<dim3(H / BN, CAP / BM, E), 256, 0, stream>>>(hbuf, w2t, b2, counts, offsets, tok_e, wgt_e, out);
}

// Round 3
// 698.988 us; speedup vs baseline: 1.1452x; 1.1104x over previous
//
#include <hip/hip_runtime.h>
#include <hip/hip_bf16.h>
#include <math.h>

// ---------- problem constants ----------
#define H 1024
#define F 4096
#define E 8
#define NTOK 4096          // B*S
#define CAP 4096           // token-list capacity per expert (2^12, used in pair packing)
#define NPAIR 8192         // NTOK * K

typedef unsigned short u16;
typedef __bf16 bf16x8 __attribute__((ext_vector_type(8)));
typedef float f32x4 __attribute__((ext_vector_type(4)));
typedef u16 u16x8 __attribute__((ext_vector_type(8)));
typedef u16 u16x4 __attribute__((ext_vector_type(4)));

__device__ inline u16 f2bf(float f) {   // RNE f32 -> bf16
    union { float f; unsigned u; } v; v.f = f;
    unsigned r = v.u + 0x7fffu + ((v.u >> 16) & 1u);
    return (u16)(r >> 16);
}

// async global->LDS, 16B per lane; LDS dest is wave-uniform base + lane*16
__device__ inline void gload_lds16(const void* g, void* l) {
    __builtin_amdgcn_global_load_lds(
        (const __attribute__((address_space(1))) unsigned*)g,
        (__attribute__((address_space(3))) unsigned*)l, 16, 0, 0);
}

// ---------- x fp32 -> bf16 ----------
__global__ void cvt_x(const float* __restrict__ x, u16* __restrict__ xb, int n8) {
    int j = blockIdx.x * blockDim.x + threadIdx.x;
    if (j >= n8) return;
    const float4* p = (const float4*)(x + (size_t)j * 8);
    float4 a = p[0], b = p[1];
    u16x8 o;
    o[0] = f2bf(a.x); o[1] = f2bf(a.y); o[2] = f2bf(a.z); o[3] = f2bf(a.w);
    o[4] = f2bf(b.x); o[5] = f2bf(b.y); o[6] = f2bf(b.z); o[7] = f2bf(b.w);
    *(u16x8*)(xb + (size_t)j * 8) = o;
}

// ---------- per-expert transpose+convert: in [R][C] f32 -> out [C][R] bf16 ----------
__global__ void transpose_cvt(const float* __restrict__ in, u16* __restrict__ out,
                              int R, int C) {
    const float* ip = in + (size_t)blockIdx.z * R * C;
    u16* op = out + (size_t)blockIdx.z * R * C;
    __shared__ float tile[64][65];
    int r0 = blockIdx.y * 64, c0 = blockIdx.x * 64;
    int tid = threadIdx.x;                 // 256 threads
    int rr = tid >> 4;
    int cc4 = (tid & 15) * 4;
    #pragma unroll
    for (int it = 0; it < 4; ++it) {
        int r = rr + it * 16;
        float4 v = *(const float4*)&ip[(size_t)(r0 + r) * C + c0 + cc4];
        tile[r][cc4 + 0] = v.x; tile[r][cc4 + 1] = v.y;
        tile[r][cc4 + 2] = v.z; tile[r][cc4 + 3] = v.w;
    }
    __syncthreads();
    int co = tid >> 3;
    int ro8 = (tid & 7) * 8;
    #pragma unroll
    for (int it = 0; it < 2; ++it) {
        int c = co + it * 32;
        u16x8 o;
        #pragma unroll
        for (int u = 0; u < 8; ++u) o[u] = f2bf(tile[ro8 + u][c]);
        *(u16x8*)&op[(size_t)(c0 + c) * R + r0 + ro8] = o;
    }
}

// ---------- router: fp32 scores, softmax top-2, bucket by expert ----------
__global__ void router_kernel(const float* __restrict__ x, const float* __restrict__ rw,
                              const float* __restrict__ rb, int* __restrict__ counts,
                              int* __restrict__ tok_e,
                              int* __restrict__ pair_id, float* __restrict__ pair_w) {
    int tok = blockIdx.x;
    int lane = threadIdx.x;       // one wave per token
    float s[E] = {0.f,0.f,0.f,0.f,0.f,0.f,0.f,0.f};
    for (int r = 0; r < 4; ++r) {
        int h = r * 256 + lane * 4;
        float4 xv = *(const float4*)&x[(size_t)tok * H + h];
        const float* xf = (const float*)&xv;
        #pragma unroll
        for (int u = 0; u < 4; ++u) {
            float xs = xf[u];
            const float4* row = (const float4*)&rw[(size_t)(h + u) * E];
            float4 a = row[0], b = row[1];
            s[0] += xs * a.x; s[1] += xs * a.y; s[2] += xs * a.z; s[3] += xs * a.w;
            s[4] += xs * b.x; s[5] += xs * b.y; s[6] += xs * b.z; s[7] += xs * b.w;
        }
    }
    #pragma unroll
    for (int off = 32; off > 0; off >>= 1)
        #pragma unroll
        for (int e2 = 0; e2 < E; ++e2) s[e2] += __shfl_down(s[e2], off);
    if (lane == 0) {
        #pragma unroll
        for (int e2 = 0; e2 < E; ++e2) s[e2] += rb[e2];
        int i0 = 0;
        #pragma unroll
        for (int e2 = 1; e2 < E; ++e2) if (s[e2] > s[i0]) i0 = e2;
        int i1 = (i0 == 0) ? 1 : 0;
        #pragma unroll
        for (int e2 = 0; e2 < E; ++e2) if (e2 != i0 && s[e2] > s[i1]) i1 = e2;
        float p0 = 1.0f / (1.0f + expf(s[i1] - s[i0]));
        float p1 = 1.0f - p0;
        int pos0 = atomicAdd(&counts[i0], 1);
        tok_e[i0 * CAP + pos0] = tok;
        int pos1 = atomicAdd(&counts[i1], 1);
        tok_e[i1 * CAP + pos1] = tok;
        pair_id[tok * 2]     = i0 * CAP + pos0;  pair_w[tok * 2]     = p0;
        pair_id[tok * 2 + 1] = i1 * CAP + pos1;  pair_w[tok * 2 + 1] = p1;
    }
}

__global__ void scan_kernel(const int* __restrict__ counts, int* __restrict__ offsets) {
    if (threadIdx.x == 0 && blockIdx.x == 0) {
        int acc = 0;
        for (int e2 = 0; e2 < E; ++e2) { offsets[e2] = acc; acc += counts[e2]; }
    }
}

// ---------- GEMM tile config ----------
#define BM 128
#define BN 128
#define BK 32
#define NBUF 3

// GEMM1: h = gelu( Xg[e] @ w1[e] + b1[e] );  A gathered via token list.
// 3-buffer LDS, 2-deep prefetch, counted vmcnt(4), 1 barrier / K-step.
__global__ __launch_bounds__(256, 3)
void gemm1_kernel(const u16* __restrict__ xb, const u16* __restrict__ w1t,
                  const float* __restrict__ b1,
                  const int* __restrict__ counts, const int* __restrict__ offsets,
                  const int* __restrict__ tok_e, u16* __restrict__ hbuf) {
    int e = blockIdx.z;
    int rows = counts[e];
    int m0 = blockIdx.y * BM;
    if (m0 >= rows) return;
    int n0 = blockIdx.x * BN;
    int off = offsets[e];
    const u16* wB = w1t + (size_t)e * F * H;   // [F][H] = B^T rows

    __shared__ u16 As[NBUF][BM * BK];   // 3 x 8KB
    __shared__ u16 Bs[NBUF][BN * BK];

    int tid = threadIdx.x, lane = tid & 63, w = tid >> 6;
    int wr = w >> 1, wc = w & 1;

    // staging: wave w owns 1KB chunks i0=2w, i1=2w+1 (16 rows each)
    int i0 = w * 2, i1 = i0 + 1;
    int rA0 = i0 * 16 + (lane >> 2), rA1 = i1 * 16 + (lane >> 2);
    int cB = (lane & 3) * 8;
    int ia0 = m0 + rA0; if (ia0 >= rows) ia0 = rows - 1;
    int ia1 = m0 + rA1; if (ia1 >= rows) ia1 = rows - 1;
    const u16* aS0 = xb + (size_t)tok_e[e * CAP + ia0] * H + cB;
    const u16* aS1 = xb + (size_t)tok_e[e * CAP + ia1] * H + cB;
    const u16* bS0 = wB + (size_t)(n0 + rA0) * H + cB;
    const u16* bS1 = wB + (size_t)(n0 + rA1) * H + cB;
    int lc0 = i0 * 512, lc1 = i1 * 512;

    int fr = lane & 15, fk = (lane >> 4) * 8;
    int aoff = (wr * 64 + fr) * BK + fk;
    int boff = (wc * 64 + fr) * BK + fk;

    f32x4 acc[4][4] = {};
    const int NT = H / BK;   // 32

    #define STAGE1(t, b) do { int kk = (t) * BK;                 \
        gload_lds16(aS0 + kk, &As[b][lc0]);                      \
        gload_lds16(aS1 + kk, &As[b][lc1]);                      \
        gload_lds16(bS0 + kk, &Bs[b][lc0]);                      \
        gload_lds16(bS1 + kk, &Bs[b][lc1]); } while (0)

    STAGE1(0, 0);
    STAGE1(1, 1);
    int b = 0;
    for (int t = 0; t < NT - 1; ++t) {
        asm volatile("s_waitcnt vmcnt(4)" ::: "memory");
        __builtin_amdgcn_s_barrier();
        __builtin_amdgcn_sched_barrier(0);
        if (t + 2 < NT) {
            int bn = b + 2; if (bn >= NBUF) bn -= NBUF;
            STAGE1(t + 2, bn);
        }
        bf16x8 af[4], bfr[4];
        #pragma unroll
        for (int m = 0; m < 4; ++m) af[m] = *(const bf16x8*)&As[b][aoff + m * 16 * BK];
        #pragma unroll
        for (int n = 0; n < 4; ++n) bfr[n] = *(const bf16x8*)&Bs[b][boff + n * 16 * BK];
        #pragma unroll
        for (int m = 0; m < 4; ++m)
            #pragma unroll
            for (int n = 0; n < 4; ++n)   // swapped operands: D[f][tok]
                acc[m][n] = __builtin_amdgcn_mfma_f32_16x16x32_bf16(bfr[n], af[m], acc[m][n], 0, 0, 0);
        ++b; if (b >= NBUF) b -= NBUF;
    }
    asm volatile("s_waitcnt vmcnt(0)" ::: "memory");
    __builtin_amdgcn_s_barrier();
    __builtin_amdgcn_sched_barrier(0);
    {
        bf16x8 af[4], bfr[4];
        #pragma unroll
        for (int m = 0; m < 4; ++m) af[m] = *(const bf16x8*)&As[b][aoff + m * 16 * BK];
        #pragma unroll
        for (int n = 0; n < 4; ++n) bfr[n] = *(const bf16x8*)&Bs[b][boff + n * 16 * BK];
        #pragma unroll
        for (int m = 0; m < 4; ++m)
            #pragma unroll
            for (int n = 0; n < 4; ++n)
                acc[m][n] = __builtin_amdgcn_mfma_f32_16x16x32_bf16(bfr[n], af[m], acc[m][n], 0, 0, 0);
    }

    // epilogue: lane owns token fr, 4 consecutive f-cols per n
    const float* b1e = b1 + (size_t)e * F;
    int c4 = (lane >> 4) * 4;
    #pragma unroll
    for (int m = 0; m < 4; ++m) {
        int r = m0 + wr * 64 + m * 16 + fr;
        if (r < rows) {
            u16* hrow = hbuf + (size_t)(off + r) * F;
            #pragma unroll
            for (int n = 0; n < 4; ++n) {
                int gc = n0 + wc * 64 + n * 16 + c4;
                float4 bv = *(const float4*)&b1e[gc];
                const float* bvf = (const float*)&bv;
                u16x4 ov;
                #pragma unroll
                for (int j = 0; j < 4; ++j) {
                    float v = acc[m][n][j] + bvf[j];
                    float g = 0.5f * v * (1.0f + erff(v * 0.70710678118654752f));
                    ov[j] = f2bf(g);
                }
                *(u16x4*)&hrow[gc] = ov;
            }
        }
    }
}

// GEMM2: obuf[pair_row] = Hg @ w2[e]   (bias+gate applied in combine)
__global__ __launch_bounds__(256, 3)
void gemm2_kernel(const u16* __restrict__ hbuf, const u16* __restrict__ w2t,
                  const int* __restrict__ counts, const int* __restrict__ offsets,
                  float* __restrict__ obuf) {
    int e = blockIdx.z;
    int rows = counts[e];
    int m0 = blockIdx.y * BM;
    if (m0 >= rows) return;
    int n0 = blockIdx.x * BN;
    int off = offsets[e];
    const u16* wB = w2t + (size_t)e * H * F;   // [H][F] = B^T rows

    __shared__ u16 As[NBUF][BM * BK];
    __shared__ u16 Bs[NBUF][BN * BK];

    int tid = threadIdx.x, lane = tid & 63, w = tid >> 6;
    int wr = w >> 1, wc = w & 1;

    int i0 = w * 2, i1 = i0 + 1;
    int rA0 = i0 * 16 + (lane >> 2), rA1 = i1 * 16 + (lane >> 2);
    int cB = (lane & 3) * 8;
    int ia0 = m0 + rA0; if (ia0 >= rows) ia0 = rows - 1;
    int ia1 = m0 + rA1; if (ia1 >= rows) ia1 = rows - 1;
    const u16* aS0 = hbuf + (size_t)(off + ia0) * F + cB;
    const u16* aS1 = hbuf + (size_t)(off + ia1) * F + cB;
    const u16* bS0 = wB + (size_t)(n0 + rA0) * F + cB;
    const u16* bS1 = wB + (size_t)(n0 + rA1) * F + cB;
    int lc0 = i0 * 512, lc1 = i1 * 512;

    int fr = lane & 15, fk = (lane >> 4) * 8;
    int aoff = (wr * 64 + fr) * BK + fk;
    int boff = (wc * 64 + fr) * BK + fk;

    f32x4 acc[4][4] = {};
    const int NT = F / BK;   // 128

    #define STAGE2(t, b) do { int kk = (t) * BK;                 \
        gload_lds16(aS0 + kk, &As[b][lc0]);                      \
        gload_lds16(aS1 + kk, &As[b][lc1]);                      \
        gload_lds16(bS0 + kk, &Bs[b][lc0]);                      \
        gload_lds16(bS1 + kk, &Bs[b][lc1]); } while (0)

    STAGE2(0, 0);
    STAGE2(1, 1);
    int b = 0;
    for (int t = 0; t < NT - 1; ++t) {
        asm volatile("s_waitcnt vmcnt(4)" ::: "memory");
        __builtin_amdgcn_s_barrier();
        __builtin_amdgcn_sched_barrier(0);
        if (t + 2 < NT) {
            int bn = b + 2; if (bn >= NBUF) bn -= NBUF;
            STAGE2(t + 2, bn);
        }
        bf16x8 af[4], bfr[4];
        #pragma unroll
        for (int m = 0; m < 4; ++m) af[m] = *(const bf16x8*)&As[b][aoff + m * 16 * BK];
        #pragma unroll
        for (int n = 0; n < 4; ++n) bfr[n] = *(const bf16x8*)&Bs[b][boff + n * 16 * BK];
        #pragma unroll
        for (int m = 0; m < 4; ++m)
            #pragma unroll
            for (int n = 0; n < 4; ++n)
                acc[m][n] = __builtin_amdgcn_mfma_f32_16x16x32_bf16(bfr[n], af[m], acc[m][n], 0, 0, 0);
        ++b; if (b >= NBUF) b -= NBUF;
    }
    asm volatile("s_waitcnt vmcnt(0)" ::: "memory");
    __builtin_amdgcn_s_barrier();
    __builtin_amdgcn_sched_barrier(0);
    {
        bf16x8 af[4], bfr[4];
        #pragma unroll
        for (int m = 0; m < 4; ++m) af[m] = *(const bf16x8*)&As[b][aoff + m * 16 * BK];
        #pragma unroll
        for (int n = 0; n < 4; ++n) bfr[n] = *(const bf16x8*)&Bs[b][boff + n * 16 * BK];
        #pragma unroll
        for (int m = 0; m < 4; ++m)
            #pragma unroll
            for (int n = 0; n < 4; ++n)
                acc[m][n] = __builtin_amdgcn_mfma_f32_16x16x32_bf16(bfr[n], af[m], acc[m][n], 0, 0, 0);
    }

    int c4 = (lane >> 4) * 4;
    #pragma unroll
    for (int m = 0; m < 4; ++m) {
        int r = m0 + wr * 64 + m * 16 + fr;
        if (r < rows) {
            float* orow = obuf + (size_t)(off + r) * H;
            #pragma unroll
            for (int n = 0; n < 4; ++n) {
                int gc = n0 + wc * 64 + n * 16 + c4;
                *(f32x4*)&orow[gc] = acc[m][n];
            }
        }
    }
}

// combine: out[tok] = w0*(obuf[r0]+b2[e0]) + w1*(obuf[r1]+b2[e1])
__global__ void combine_kernel(const float* __restrict__ obuf, const float* __restrict__ b2,
                               const int* __restrict__ offsets,
                               const int* __restrict__ pair_id, const float* __restrict__ pair_w,
                               float* __restrict__ out) {
    int tok = blockIdx.x;
    int c4 = threadIdx.x * 4;
    int p0 = pair_id[tok * 2], p1 = pair_id[tok * 2 + 1];
    float w0 = pair_w[tok * 2], w1 = pair_w[tok * 2 + 1];
    int e0 = p0 >> 12, e1 = p1 >> 12;
    int r0 = offsets[e0] + (p0 & (CAP - 1));
    int r1 = offsets[e1] + (p1 & (CAP - 1));
    f32x4 a  = *(const f32x4*)&obuf[(size_t)r0 * H + c4];
    f32x4 bb = *(const f32x4*)&obuf[(size_t)r1 * H + c4];
    f32x4 ba0 = *(const f32x4*)&b2[(size_t)e0 * H + c4];
    f32x4 ba1 = *(const f32x4*)&b2[(size_t)e1 * H + c4];
    f32x4 r;
    #pragma unroll
    for (int j = 0; j < 4; ++j)
        r[j] = w0 * (a[j] + ba0[j]) + w1 * (bb[j] + ba1[j]);
    *(f32x4*)&out[(size_t)tok * H + c4] = r;
}

// ---------- launch ----------
extern "C" void kernel_launch(void* const* d_in, const int* in_sizes, int n_in,
                              void* d_out, int out_size, void* d_ws, size_t ws_size,
                              hipStream_t stream) {
    const float* x  = (const float*)d_in[0];
    const float* rw = (const float*)d_in[1];
    const float* rb = (const float*)d_in[2];
    const float* w1 = (const float*)d_in[3];
    const float* b1 = (const float*)d_in[4];
    const float* w2 = (const float*)d_in[5];
    const float* b2 = (const float*)d_in[6];
    float* out = (float*)d_out;

    char* ws = (char*)d_ws;
    size_t o = 0;
    u16* xb   = (u16*)(ws + o); o += (size_t)NTOK * H * 2;        // 8 MB
    u16* w1t  = (u16*)(ws + o); o += (size_t)E * F * H * 2;       // 64 MB [E][F][H]
    u16* w2t  = (u16*)(ws + o); o += (size_t)E * H * F * 2;       // 64 MB [E][H][F]
    u16* hbuf = (u16*)(ws + o); o += (size_t)NPAIR * F * 2;       // 64 MB
    float* obuf = (float*)(ws + o); o += (size_t)NPAIR * H * 4;   // 32 MB
    int*   tok_e   = (int*)(ws + o); o += (size_t)E * CAP * 4;
    int*   pair_id = (int*)(ws + o); o += (size_t)NTOK * 2 * 4;
    float* pair_w  = (float*)(ws + o); o += (size_t)NTOK * 2 * 4;
    int*   counts  = (int*)(ws + o); o += E * 4;
    int*   offsets = (int*)(ws + o); o += E * 4;

    hipMemsetAsync(counts, 0, 2 * E * sizeof(int), stream);

    cvt_x<<<(NTOK * H / 8 + 255) / 256, 256, 0, stream>>>(x, xb, NTOK * H / 8);
    transpose_cvt<<<dim3(F / 64, H / 64, E), 256, 0, stream>>>(w1, w1t, H, F);
    transpose_cvt<<<dim3(H / 64, F / 64, E), 256, 0, stream>>>(w2, w2t, F, H);
    router_kernel<<<NTOK, 64, 0, stream>>>(x, rw, rb, counts, tok_e, pair_id, pair_w);
    scan_kernel<<<1, 64, 0, stream>>>(counts, offsets);
    gemm1_kernel<<<dim3(F / BN, CAP / BM, E), 256, 0, stream>>>(xb, w1t, b1, counts, offsets, tok_e, hbuf);
    gemm2_kernel<<<dim3(H / BN, CAP / BM, E), 256, 0, stream>>>(hbuf, w2t, counts, offsets, obuf);
    combine_kernel<<<NTOK, 256, 0, stream>>>(obuf, b2, offsets, pair_id, pair_w, out);
}